// Round 4
// baseline (1296.054 us; speedup 1.0000x reference)
//
#include <hip/hip_runtime.h>

#define T_STEPS 250
#define BATCH   256
#define IN_DIM  700
#define HID     1024
#define W_LD    1724   // = IN_DIM + HID
#define OUT_DIM 20
#define KP      704    // K padded to 22*32
#define KP4     (KP / 4)
#define NKT     (KP / 32)

typedef __attribute__((ext_vector_type(8))) short     bf16x8;
typedef __attribute__((ext_vector_type(8))) unsigned short u16x8;
typedef __attribute__((ext_vector_type(4))) float     f32x4;
typedef unsigned long long u64;

__device__ inline unsigned short f2bf(float f) {
    unsigned int u = __float_as_uint(f);
    unsigned int r = u + 0x7FFFu + ((u >> 16) & 1u);
    return (unsigned short)(r >> 16);
}
__device__ inline float bf2f(unsigned short w) {
    return __uint_as_float(((unsigned int)w) << 16);
}

// ---------------------------------------------------------------------------
// WhhT_bf16[j][h] = bf16(W_h[h][700 + j]);  row 1024 is a zero sentinel row.
// ---------------------------------------------------------------------------
__global__ __launch_bounds__(256)
void trans_whh_bf16(const float* __restrict__ W_h, unsigned short* __restrict__ WhhT) {
    __shared__ float tile[32][33];
    const int bx = blockIdx.x * 32;  // h base
    const int by = blockIdx.y * 32;  // j base
    const int tx = threadIdx.x, ty = threadIdx.y;
#pragma unroll
    for (int i = 0; i < 32; i += 8)
        tile[ty + i][tx] = W_h[(size_t)(bx + ty + i) * W_LD + IN_DIM + by + tx];
    __syncthreads();
#pragma unroll
    for (int i = 0; i < 32; i += 8)
        WhhT[(size_t)(by + ty + i) * HID + bx + tx] = f2bf(tile[tx][ty + i]);
}

// WoT[h][o] = Wo[o][h]
__global__ __launch_bounds__(256)
void trans_wo(const float* __restrict__ Wo, float* __restrict__ WoT) {
    const int h = blockIdx.x * 256 + threadIdx.x;
    if (h >= HID) return;
#pragma unroll
    for (int o = 0; o < OUT_DIM; ++o)
        WoT[(size_t)h * OUT_DIM + o] = Wo[(size_t)o * HID + h];
}

// ---------------------------------------------------------------------------
// Pack x rows -> zero-padded K=704 bf16
// ---------------------------------------------------------------------------
__global__ __launch_bounds__(256)
void pack_x_bf16(const float* __restrict__ x, unsigned short* __restrict__ Xp, int rows) {
    const int total = rows * KP4;
    for (int idx = blockIdx.x * blockDim.x + threadIdx.x; idx < total;
         idx += gridDim.x * blockDim.x) {
        const int r = idx / KP4;
        const int c = idx - r * KP4;
        ushort4 o = make_ushort4(0, 0, 0, 0);
        if (c < IN_DIM / 4) {
            float4 v = *(const float4*)(x + (size_t)r * IN_DIM + c * 4);
            o = make_ushort4(f2bf(v.x), f2bf(v.y), f2bf(v.z), f2bf(v.w));
        }
        ((ushort4*)Xp)[(size_t)r * KP4 + c] = o;
    }
}

// Pack W_h's first 700 cols (ld 1724) -> [1024][704] bf16
__global__ __launch_bounds__(256)
void pack_w_bf16(const float* __restrict__ W_h, unsigned short* __restrict__ Wp) {
    const int total = HID * KP4;
    for (int idx = blockIdx.x * blockDim.x + threadIdx.x; idx < total;
         idx += gridDim.x * blockDim.x) {
        const int r = idx / KP4;
        const int c = idx - r * KP4;
        ushort4 o = make_ushort4(0, 0, 0, 0);
        if (c < IN_DIM / 4) {
            float4 v = *(const float4*)(W_h + (size_t)r * W_LD + c * 4);
            o = make_ushort4(f2bf(v.x), f2bf(v.y), f2bf(v.z), f2bf(v.w));
        }
        ((ushort4*)Wp)[(size_t)r * KP4 + c] = o;
    }
}

// ---------------------------------------------------------------------------
// bf16 MFMA GEMM (unchanged from round 3): 128x128 tile, BK=32, 4 waves.
// ---------------------------------------------------------------------------
__global__ __launch_bounds__(256)
void mfma_gemm(const unsigned short* __restrict__ A,
               const unsigned short* __restrict__ B, float* __restrict__ C) {
    __shared__ unsigned short lA[128 * 32];
    __shared__ unsigned short lB[128 * 32];
    const int tid  = threadIdx.x;
    const int wid  = tid >> 6, lane = tid & 63;
    const int wr   = wid >> 1, wc = wid & 1;
    const size_t bm = (size_t)blockIdx.x * 128;
    const size_t bn = (size_t)blockIdx.y * 128;

    const int srow = tid >> 2;
    const int skq  = (tid & 3) * 8;

    const int wb0 = (srow * 64 + (tid & 3) * 16) ^ ((srow & 7) << 4);
    const int wb1 = ((srow + 64) * 64 + (tid & 3) * 16) ^ ((srow & 7) << 4);

    const unsigned short* pa = A + (bm + srow) * KP + skq;
    const unsigned short* pb = B + (bn + srow) * KP + skq;

    u16x8 ra0, ra1, rb0, rb1;
    auto ldg = [&](int k0) {
        ra0 = *(const u16x8*)(pa + k0);
        ra1 = *(const u16x8*)(pa + (size_t)64 * KP + k0);
        rb0 = *(const u16x8*)(pb + k0);
        rb1 = *(const u16x8*)(pb + (size_t)64 * KP + k0);
    };

    const int arow = wr * 64 + (lane & 15);
    const int brow = wc * 64 + (lane & 15);
    const int fq   = (lane >> 4) * 16;

    f32x4 acc[4][4];
#pragma unroll
    for (int m = 0; m < 4; ++m)
#pragma unroll
        for (int n = 0; n < 4; ++n) acc[m][n] = (f32x4){0.f, 0.f, 0.f, 0.f};

    ldg(0);
    for (int kt = 0; kt < NKT; ++kt) {
        *(u16x8*)((char*)lA + wb0) = ra0;
        *(u16x8*)((char*)lA + wb1) = ra1;
        *(u16x8*)((char*)lB + wb0) = rb0;
        *(u16x8*)((char*)lB + wb1) = rb1;
        __syncthreads();
        if (kt + 1 < NKT) ldg((kt + 1) * 32);
        bf16x8 af[4], bf[4];
#pragma unroll
        for (int m = 0; m < 4; ++m) {
            const int row = arow + m * 16;
            af[m] = *(const bf16x8*)((const char*)lA + ((row * 64 + fq) ^ ((row & 7) << 4)));
        }
#pragma unroll
        for (int n = 0; n < 4; ++n) {
            const int row = brow + n * 16;
            bf[n] = *(const bf16x8*)((const char*)lB + ((row * 64 + fq) ^ ((row & 7) << 4)));
        }
#pragma unroll
        for (int m = 0; m < 4; ++m)
#pragma unroll
            for (int n = 0; n < 4; ++n)
                acc[m][n] = __builtin_amdgcn_mfma_f32_16x16x32_bf16(af[m], bf[n], acc[m][n], 0, 0, 0);
        __syncthreads();
    }
#pragma unroll
    for (int m = 0; m < 4; ++m)
#pragma unroll
        for (int r = 0; r < 4; ++r) {
            float* cp = C + (bm + wr * 64 + m * 16 + (lane >> 4) * 4 + r) * HID
                          + bn + wc * 64 + (lane & 15);
#pragma unroll
            for (int n = 0; n < 4; ++n) cp[n * 16] = acc[m][n][r];
        }
}

// ---------------------------------------------------------------------------
// Persistent ALIF scan v2: 1 block/batch, 128 threads, 8 neurons/thread.
// u16x8 weight gathers (16B/spike/thread), per-wave spike-list segments,
// 1 barrier/step, 16-deep load batching with zero sentinel row.
// ---------------------------------------------------------------------------
__global__ __launch_bounds__(128)
void alif_scan(const float* __restrict__ CUR, const unsigned short* __restrict__ WhhT,
               const float* __restrict__ tau_mem, const float* __restrict__ tau_adp,
               float* __restrict__ zS, float* __restrict__ uS, float* __restrict__ aS,
               float* __restrict__ spkS, unsigned char* __restrict__ masksB,
               int t0, int tc) {
    const int b    = blockIdx.x;
    const int i    = threadIdx.x;       // 0..127
    const int h0   = i * 8;
    const int wv   = i >> 6;            // wave 0/1
    const int lane = i & 63;

    __shared__ unsigned short s_list[2][2][512];  // [buf][wave-seg][slot]
    __shared__ int s_cnt[2][2];
    __shared__ int s_spk;

    float u[8], a[8], alpha[8], oma[8], rho[8], omr[8];
#pragma unroll
    for (int k = 0; k < 8; ++k) {
        u[k]     = uS[(size_t)b * HID + h0 + k];
        a[k]     = aS[(size_t)b * HID + h0 + k];
        alpha[k] = expf(-1.f / tau_mem[h0 + k]);
        oma[k]   = 1.f - alpha[k];
        rho[k]   = expf(-1.f / tau_adp[h0 + k]);
        omr[k]   = 1.f - rho[k];
    }
    unsigned int zb = 0;
#pragma unroll
    for (int k = 0; k < 8; ++k)
        if (zS[(size_t)b * HID + h0 + k] > 0.5f) zb |= (1u << k);
    if (i == 0) s_spk = 0;

    // scatter carried-in spikes into list buf 0 (per-wave segment)
    {
        const int cnt = __popc(zb);
        int incl = cnt;
#pragma unroll
        for (int d = 1; d < 64; d <<= 1) {
            int v = __shfl_up(incl, d, 64);
            if (lane >= d) incl += v;
        }
        int off = incl - cnt;
        unsigned int tmp = zb;
        while (tmp) {
            const int k = __ffs(tmp) - 1;
            tmp &= tmp - 1;
            s_list[0][wv][off++] = (unsigned short)(h0 + k);
        }
        if (lane == 63) s_cnt[0][wv] = incl;
    }

    const unsigned short* Wrow = WhhT + h0;
    float xc[8];
    {
        const float4* p = (const float4*)(CUR + (size_t)b * HID + h0);
        float4 v0 = p[0], v1 = p[1];
        xc[0]=v0.x; xc[1]=v0.y; xc[2]=v0.z; xc[3]=v0.w;
        xc[4]=v1.x; xc[5]=v1.y; xc[6]=v1.z; xc[7]=v1.w;
    }
    __syncthreads();

    int cur = 0;
    int wspk = 0;
    for (int tt = 0; tt < tc; ++tt) {
        // prefetch next step's input current (hide HBM latency under gather)
        float xn[8];
        {
            const int tn = (tt + 1 < tc) ? tt + 1 : tt;
            const float4* p = (const float4*)(CUR + ((size_t)tn * BATCH + b) * HID + h0);
            float4 v0 = p[0], v1 = p[1];
            xn[0]=v0.x; xn[1]=v0.y; xn[2]=v0.z; xn[3]=v0.w;
            xn[4]=v1.x; xn[5]=v1.y; xn[6]=v1.z; xn[7]=v1.w;
        }

        float rec[8];
#pragma unroll
        for (int k = 0; k < 8; ++k) rec[k] = 0.f;

#pragma unroll 1
        for (int seg = 0; seg < 2; ++seg) {
            const int ns = s_cnt[cur][seg];
            const unsigned short* lst = s_list[cur][seg];
#pragma unroll 1
            for (int base = 0; base < ns; base += 16) {
                int j[16];
#pragma unroll
                for (int q = 0; q < 16; ++q) {
                    const int idx = base + q;
                    j[q] = (idx < ns) ? (int)lst[idx] : 1024;  // 1024 = zero row
                }
                u16x8 wvv[16];
#pragma unroll
                for (int q = 0; q < 16; ++q)
                    wvv[q] = *(const u16x8*)(Wrow + ((size_t)j[q] << 10));
#pragma unroll
                for (int q = 0; q < 16; ++q)
#pragma unroll
                    for (int k = 0; k < 8; ++k)
                        rec[k] += bf2f((unsigned short)wvv[q][k]);
            }
        }

        // neuron update
        unsigned int znb = 0;
#pragma unroll
        for (int k = 0; k < 8; ++k) {
            const float z = (zb >> k) & 1 ? 1.f : 0.f;
            a[k] = rho[k] * a[k] + omr[k] * z;
            const float th = 0.01f + 1.8f * a[k];
            u[k] = alpha[k] * u[k] + oma[k] * (xc[k] + rec[k]) - z * th;
            if (u[k] - th > 0.f) znb |= (1u << k);
        }
        zb = znb;
        wspk += __popc(zb);
        masksB[(((size_t)(t0 + tt) * BATCH + b) << 7) + i] = (unsigned char)zb;

        // scatter new spikes into the other buffer (per-wave segment)
        {
            const int cnt = __popc(zb);
            int incl = cnt;
#pragma unroll
            for (int d = 1; d < 64; d <<= 1) {
                int v = __shfl_up(incl, d, 64);
                if (lane >= d) incl += v;
            }
            int off = incl - cnt;
            unsigned int tmp = zb;
            while (tmp) {
                const int k = __ffs(tmp) - 1;
                tmp &= tmp - 1;
                s_list[cur ^ 1][wv][off++] = (unsigned short)(h0 + k);
            }
            if (lane == 63) s_cnt[cur ^ 1][wv] = incl;
        }
#pragma unroll
        for (int k = 0; k < 8; ++k) xc[k] = xn[k];
        __syncthreads();
        cur ^= 1;
    }

    // write back state
#pragma unroll
    for (int k = 0; k < 8; ++k) {
        zS[(size_t)b * HID + h0 + k] = (zb >> k) & 1 ? 1.f : 0.f;
        uS[(size_t)b * HID + h0 + k] = u[k];
        aS[(size_t)b * HID + h0 + k] = a[k];
    }
#pragma unroll
    for (int d = 32; d > 0; d >>= 1) wspk += __shfl_down(wspk, d, 64);
    if (lane == 0) atomicAdd(&s_spk, wspk);
    __syncthreads();
    if (i == 0 && s_spk) atomicAdd(spkS, (float)s_spk);
}

// ---------------------------------------------------------------------------
// y[t*B+b][o] = sum over spiking j of WoT[j][o]  (one wave per (t,b) pair)
// ---------------------------------------------------------------------------
__global__ __launch_bounds__(256)
void readout_y(const u64* __restrict__ masks, const float* __restrict__ WoT,
               float* __restrict__ y, int npairs) {
    const int pr   = blockIdx.x * 4 + (threadIdx.x >> 6);
    const int lane = threadIdx.x & 63;
    if (pr >= npairs) return;
    const u64* mp = masks + (size_t)pr * 16;
    float acc = 0.f;
#pragma unroll 4
    for (int w = 0; w < 16; ++w) {
        u64 m = mp[w];
        while (m) {
            const int j = __ffsll((unsigned long long)m) - 1;
            m &= m - 1;
            if (lane < OUT_DIM) acc += WoT[(size_t)(w * 64 + j) * OUT_DIM + lane];
        }
    }
    if (lane < OUT_DIM) y[(size_t)pr * OUT_DIM + lane] = acc;
}

// ---------------------------------------------------------------------------
// outputs[t][b][o] = EWA over t of y; writes final ouT.
// ---------------------------------------------------------------------------
__global__ __launch_bounds__(256)
void ewa_out(const float* __restrict__ y, const float* __restrict__ tau_out,
             float* __restrict__ outputs, float* __restrict__ ouS) {
    const int idx = blockIdx.x * 256 + threadIdx.x;
    if (idx >= BATCH * OUT_DIM) return;
    const int o = idx % OUT_DIM;
    const float ao = expf(-1.f / tau_out[o]);
    float ou = ouS[idx];
    for (int t = 0; t < T_STEPS; ++t) {
        const float v = y[(size_t)t * BATCH * OUT_DIM + idx];
        ou = ao * ou + (1.f - ao) * v;
        outputs[(size_t)t * BATCH * OUT_DIM + idx] = ou;
    }
    ouS[idx] = ou;
}

// ---------------------------------------------------------------------------
extern "C" void kernel_launch(void* const* d_in, const int* in_sizes, int n_in,
                              void* d_out, int out_size, void* d_ws, size_t ws_size,
                              hipStream_t stream) {
    (void)in_sizes; (void)n_in; (void)out_size;
    const float* x       = (const float*)d_in[0];
    const float* W_h     = (const float*)d_in[1];
    const float* tau_mem = (const float*)d_in[2];
    const float* tau_adp = (const float*)d_in[3];
    const float* W_o     = (const float*)d_in[4];
    const float* tau_out = (const float*)d_in[5];

    float* out     = (float*)d_out;
    float* outputs = out;                                      // [250][256][20]
    float* zS  = out + (size_t)T_STEPS * BATCH * OUT_DIM;      // [256][1024]
    float* uS  = zS + (size_t)BATCH * HID;
    float* aS  = uS + (size_t)BATCH * HID;
    float* ouS = aS + (size_t)BATCH * HID;                     // [256][20]
    float* spk = ouS + (size_t)BATCH * OUT_DIM;                // scalar

    // ws layout (bytes)
    char* w = (char*)d_ws;
    unsigned short* WhhT = (unsigned short*)w; w += (size_t)(HID + 1) * HID * 2;  // 2 MB + zero row
    unsigned short* Wp   = (unsigned short*)w; w += (size_t)HID * KP * 2;         // 1.4 MB
    float*          WoT  = (float*)w;          w += (size_t)HID * OUT_DIM * 4;    // 80 KB
    unsigned char*  masksB = (unsigned char*)w; w += (size_t)T_STEPS * BATCH * 128; // 8 MB
    float*          yBuf = (float*)w;          w += (size_t)T_STEPS * BATCH * OUT_DIM * 4; // 5 MB
    char*           dynb = w;

    const size_t fixed = (size_t)(dynb - (char*)d_ws);
    const size_t per_step = (size_t)BATCH * KP * 2 + (size_t)BATCH * HID * 4;
    const size_t avail = ws_size > fixed ? ws_size - fixed : 0;
    int CT = (int)(avail / per_step);
    if (CT > T_STEPS) CT = T_STEPS;
    if (CT < 1) CT = 1;

    hipMemsetAsync(zS, 0,
                   ((size_t)3 * BATCH * HID + BATCH * OUT_DIM + 1) * sizeof(float),
                   stream);
    hipMemsetAsync(WhhT + (size_t)HID * HID, 0, HID * sizeof(unsigned short), stream);
    trans_whh_bf16<<<dim3(32, 32), dim3(32, 8), 0, stream>>>(W_h, WhhT);
    pack_w_bf16<<<512, 256, 0, stream>>>(W_h, Wp);
    trans_wo<<<4, 256, 0, stream>>>(W_o, WoT);

    for (int t0 = 0; t0 < T_STEPS; t0 += CT) {
        const int tc = (T_STEPS - t0 < CT) ? (T_STEPS - t0) : CT;
        const int rows = tc * BATCH;
        unsigned short* Xp = (unsigned short*)dynb;
        float* CUR = (float*)(dynb + (size_t)rows * KP * 2);
        int pblocks = (rows * KP4 + 255) / 256;
        if (pblocks > 2048) pblocks = 2048;
        pack_x_bf16<<<pblocks, 256, 0, stream>>>(x + (size_t)t0 * BATCH * IN_DIM, Xp, rows);
        mfma_gemm<<<dim3(rows / 128, HID / 128), 256, 0, stream>>>(Xp, Wp, CUR);
        alif_scan<<<BATCH, 128, 0, stream>>>(CUR, WhhT, tau_mem, tau_adp,
                                             zS, uS, aS, spk, masksB, t0, tc);
    }

    const int npairs = T_STEPS * BATCH;
    readout_y<<<(npairs + 3) / 4, 256, 0, stream>>>((const u64*)masksB, WoT, yBuf, npairs);
    ewa_out<<<(BATCH * OUT_DIM + 255) / 256, 256, 0, stream>>>(yBuf, tau_out, outputs, ouS);
}

// Round 5
// 1232.186 us; speedup vs baseline: 1.0518x; 1.0518x over previous
//
#include <hip/hip_runtime.h>

#define T_STEPS 250
#define BATCH   256
#define IN_DIM  700
#define HID     1024
#define W_LD    1724   // = IN_DIM + HID
#define OUT_DIM 20
#define KP      704    // K padded to 22*32
#define KP4     (KP / 4)
#define NKT     (KP / 32)

typedef __attribute__((ext_vector_type(8))) short     bf16x8;
typedef __attribute__((ext_vector_type(8))) unsigned short u16x8;
typedef __attribute__((ext_vector_type(4))) float     f32x4;
typedef unsigned long long u64;

__device__ inline unsigned short f2bf(float f) {
    unsigned int u = __float_as_uint(f);
    unsigned int r = u + 0x7FFFu + ((u >> 16) & 1u);
    return (unsigned short)(r >> 16);
}
__device__ inline float bf2f(unsigned short w) {
    return __uint_as_float(((unsigned int)w) << 16);
}

// ---------------------------------------------------------------------------
// WhhT_bf16[j][h] = bf16(W_h[h][700 + j]);  row 1024 is a zero sentinel row.
// ---------------------------------------------------------------------------
__global__ __launch_bounds__(256)
void trans_whh_bf16(const float* __restrict__ W_h, unsigned short* __restrict__ WhhT) {
    __shared__ float tile[32][33];
    const int bx = blockIdx.x * 32;  // h base
    const int by = blockIdx.y * 32;  // j base
    const int tx = threadIdx.x, ty = threadIdx.y;
#pragma unroll
    for (int i = 0; i < 32; i += 8)
        tile[ty + i][tx] = W_h[(size_t)(bx + ty + i) * W_LD + IN_DIM + by + tx];
    __syncthreads();
#pragma unroll
    for (int i = 0; i < 32; i += 8)
        WhhT[(size_t)(by + ty + i) * HID + bx + tx] = f2bf(tile[tx][ty + i]);
}

// WoT[h][o] = Wo[o][h]
__global__ __launch_bounds__(256)
void trans_wo(const float* __restrict__ Wo, float* __restrict__ WoT) {
    const int h = blockIdx.x * 256 + threadIdx.x;
    if (h >= HID) return;
#pragma unroll
    for (int o = 0; o < OUT_DIM; ++o)
        WoT[(size_t)h * OUT_DIM + o] = Wo[(size_t)o * HID + h];
}

// ---------------------------------------------------------------------------
// Pack x rows -> zero-padded K=704 bf16
// ---------------------------------------------------------------------------
__global__ __launch_bounds__(256)
void pack_x_bf16(const float* __restrict__ x, unsigned short* __restrict__ Xp, int rows) {
    const int total = rows * KP4;
    for (int idx = blockIdx.x * blockDim.x + threadIdx.x; idx < total;
         idx += gridDim.x * blockDim.x) {
        const int r = idx / KP4;
        const int c = idx - r * KP4;
        ushort4 o = make_ushort4(0, 0, 0, 0);
        if (c < IN_DIM / 4) {
            float4 v = *(const float4*)(x + (size_t)r * IN_DIM + c * 4);
            o = make_ushort4(f2bf(v.x), f2bf(v.y), f2bf(v.z), f2bf(v.w));
        }
        ((ushort4*)Xp)[(size_t)r * KP4 + c] = o;
    }
}

// Pack W_h's first 700 cols (ld 1724) -> [1024][704] bf16
__global__ __launch_bounds__(256)
void pack_w_bf16(const float* __restrict__ W_h, unsigned short* __restrict__ Wp) {
    const int total = HID * KP4;
    for (int idx = blockIdx.x * blockDim.x + threadIdx.x; idx < total;
         idx += gridDim.x * blockDim.x) {
        const int r = idx / KP4;
        const int c = idx - r * KP4;
        ushort4 o = make_ushort4(0, 0, 0, 0);
        if (c < IN_DIM / 4) {
            float4 v = *(const float4*)(W_h + (size_t)r * W_LD + c * 4);
            o = make_ushort4(f2bf(v.x), f2bf(v.y), f2bf(v.z), f2bf(v.w));
        }
        ((ushort4*)Wp)[(size_t)r * KP4 + c] = o;
    }
}

// ---------------------------------------------------------------------------
// bf16 MFMA GEMM: 128x128 tile, BK=32, 4 waves. (unchanged)
// ---------------------------------------------------------------------------
__global__ __launch_bounds__(256)
void mfma_gemm(const unsigned short* __restrict__ A,
               const unsigned short* __restrict__ B, float* __restrict__ C) {
    __shared__ unsigned short lA[128 * 32];
    __shared__ unsigned short lB[128 * 32];
    const int tid  = threadIdx.x;
    const int wid  = tid >> 6, lane = tid & 63;
    const int wr   = wid >> 1, wc = wid & 1;
    const size_t bm = (size_t)blockIdx.x * 128;
    const size_t bn = (size_t)blockIdx.y * 128;

    const int srow = tid >> 2;
    const int skq  = (tid & 3) * 8;

    const int wb0 = (srow * 64 + (tid & 3) * 16) ^ ((srow & 7) << 4);
    const int wb1 = ((srow + 64) * 64 + (tid & 3) * 16) ^ ((srow & 7) << 4);

    const unsigned short* pa = A + (bm + srow) * KP + skq;
    const unsigned short* pb = B + (bn + srow) * KP + skq;

    u16x8 ra0, ra1, rb0, rb1;
    auto ldg = [&](int k0) {
        ra0 = *(const u16x8*)(pa + k0);
        ra1 = *(const u16x8*)(pa + (size_t)64 * KP + k0);
        rb0 = *(const u16x8*)(pb + k0);
        rb1 = *(const u16x8*)(pb + (size_t)64 * KP + k0);
    };

    const int arow = wr * 64 + (lane & 15);
    const int brow = wc * 64 + (lane & 15);
    const int fq   = (lane >> 4) * 16;

    f32x4 acc[4][4];
#pragma unroll
    for (int m = 0; m < 4; ++m)
#pragma unroll
        for (int n = 0; n < 4; ++n) acc[m][n] = (f32x4){0.f, 0.f, 0.f, 0.f};

    ldg(0);
    for (int kt = 0; kt < NKT; ++kt) {
        *(u16x8*)((char*)lA + wb0) = ra0;
        *(u16x8*)((char*)lA + wb1) = ra1;
        *(u16x8*)((char*)lB + wb0) = rb0;
        *(u16x8*)((char*)lB + wb1) = rb1;
        __syncthreads();
        if (kt + 1 < NKT) ldg((kt + 1) * 32);
        bf16x8 af[4], bf[4];
#pragma unroll
        for (int m = 0; m < 4; ++m) {
            const int row = arow + m * 16;
            af[m] = *(const bf16x8*)((const char*)lA + ((row * 64 + fq) ^ ((row & 7) << 4)));
        }
#pragma unroll
        for (int n = 0; n < 4; ++n) {
            const int row = brow + n * 16;
            bf[n] = *(const bf16x8*)((const char*)lB + ((row * 64 + fq) ^ ((row & 7) << 4)));
        }
#pragma unroll
        for (int m = 0; m < 4; ++m)
#pragma unroll
            for (int n = 0; n < 4; ++n)
                acc[m][n] = __builtin_amdgcn_mfma_f32_16x16x32_bf16(af[m], bf[n], acc[m][n], 0, 0, 0);
        __syncthreads();
    }
#pragma unroll
    for (int m = 0; m < 4; ++m)
#pragma unroll
        for (int r = 0; r < 4; ++r) {
            float* cp = C + (bm + wr * 64 + m * 16 + (lane >> 4) * 4 + r) * HID
                          + bn + wc * 64 + (lane & 15);
#pragma unroll
            for (int n = 0; n < 4; ++n) cp[n * 16] = acc[m][n][r];
        }
}

// ---------------------------------------------------------------------------
// Persistent ALIF scan v3: 1 block = 1 wave = 1 batch, 16 neurons/lane.
// Wave-synchronous: no inter-wave deps; double-buffered LDS spike list;
// flat 1-round-trip gather with zero sentinel row; ascending-j sum order
// (bitwise-identical trajectory to rounds 3/4).
// ---------------------------------------------------------------------------
__global__ __launch_bounds__(64)
void alif_scan(const float* __restrict__ CUR, const unsigned short* __restrict__ WhhT,
               const float* __restrict__ tau_mem, const float* __restrict__ tau_adp,
               float* __restrict__ zS, float* __restrict__ uS, float* __restrict__ aS,
               float* __restrict__ spkS, unsigned short* __restrict__ masks16,
               int t0, int tc) {
    const int b    = blockIdx.x;
    const int lane = threadIdx.x;      // 0..63
    const int h0   = lane * 16;

    __shared__ __align__(16) unsigned short s_idx[2][1040];

    float u[16], a[16], alpha[16], oma[16], rho[16], omr[16];
#pragma unroll
    for (int q = 0; q < 4; ++q) {
        f32x4 uu = *(const f32x4*)(uS + (size_t)b * HID + h0 + q * 4);
        f32x4 aa = *(const f32x4*)(aS + (size_t)b * HID + h0 + q * 4);
        f32x4 tm = *(const f32x4*)(tau_mem + h0 + q * 4);
        f32x4 ta = *(const f32x4*)(tau_adp + h0 + q * 4);
#pragma unroll
        for (int k = 0; k < 4; ++k) {
            u[q * 4 + k]     = uu[k];
            a[q * 4 + k]     = aa[k];
            alpha[q * 4 + k] = expf(-1.f / tm[k]);
            oma[q * 4 + k]   = 1.f - alpha[q * 4 + k];
            rho[q * 4 + k]   = expf(-1.f / ta[k]);
            omr[q * 4 + k]   = 1.f - rho[q * 4 + k];
        }
    }
    unsigned int zb = 0;
#pragma unroll
    for (int q = 0; q < 4; ++q) {
        f32x4 zz = *(const f32x4*)(zS + (size_t)b * HID + h0 + q * 4);
#pragma unroll
        for (int k = 0; k < 4; ++k)
            if (zz[k] > 0.5f) zb |= (1u << (q * 4 + k));
    }

    // build initial spike list into buffer 0
    int n;
    {
        const int cnt = __popc(zb);
        int incl = cnt;
#pragma unroll
        for (int d = 1; d < 64; d <<= 1) {
            int v = __shfl_up(incl, d, 64);
            if (lane >= d) incl += v;
        }
        int off = incl - cnt;
        unsigned int tmp = zb;
        while (tmp) {
            const int k = __ffs(tmp) - 1;
            tmp &= tmp - 1;
            s_idx[0][off++] = (unsigned short)(h0 + k);
        }
        n = __shfl(incl, 63, 64);
    }

    const unsigned short* Wrow = WhhT + h0;
    float xc[16];
#pragma unroll
    for (int q = 0; q < 4; ++q) {
        f32x4 v = *(const f32x4*)(CUR + (size_t)b * HID + h0 + q * 4);
        xc[q * 4 + 0] = v[0]; xc[q * 4 + 1] = v[1];
        xc[q * 4 + 2] = v[2]; xc[q * 4 + 3] = v[3];
    }
    __syncthreads();

    int cur = 0;
    int wspk = 0;
    for (int tt = 0; tt < tc; ++tt) {
        // prefetch next step's input current
        float xn[16];
        {
            const int tn = (tt + 1 < tc) ? tt + 1 : tt;
            const float* p = CUR + ((size_t)tn * BATCH + b) * HID + h0;
#pragma unroll
            for (int q = 0; q < 4; ++q) {
                f32x4 v = *(const f32x4*)(p + q * 4);
                xn[q * 4 + 0] = v[0]; xn[q * 4 + 1] = v[1];
                xn[q * 4 + 2] = v[2]; xn[q * 4 + 3] = v[3];
            }
        }

        float rec[16];
#pragma unroll
        for (int k = 0; k < 16; ++k) rec[k] = 0.f;

#pragma unroll 1
        for (int i = 0; i < n; i += 8) {
            const u16x8 idx8 = *(const u16x8*)&s_idx[cur][i];  // broadcast read
#pragma unroll
            for (int q = 0; q < 8; ++q) {
                const int j = (i + q < n) ? (int)idx8[q] : 1024;  // 1024 = zero row
                const u16x8 w0 = *(const u16x8*)(Wrow + ((size_t)j << 10));
                const u16x8 w1 = *(const u16x8*)(Wrow + ((size_t)j << 10) + 8);
#pragma unroll
                for (int k = 0; k < 8; ++k) {
                    rec[k]     += bf2f((unsigned short)w0[k]);
                    rec[k + 8] += bf2f((unsigned short)w1[k]);
                }
            }
        }

        // neuron update
        unsigned int znb = 0;
#pragma unroll
        for (int k = 0; k < 16; ++k) {
            const float z = (zb >> k) & 1 ? 1.f : 0.f;
            a[k] = rho[k] * a[k] + omr[k] * z;
            const float th = 0.01f + 1.8f * a[k];
            u[k] = alpha[k] * u[k] + oma[k] * (xc[k] + rec[k]) - z * th;
            if (u[k] - th > 0.f) znb |= (1u << k);
        }
        zb = znb;
        wspk += __popc(zb);
        masks16[((size_t)(t0 + tt) * BATCH + b) * 64 + lane] = (unsigned short)zb;

        // build next spike list into the other buffer
        {
            const int cnt = __popc(zb);
            int incl = cnt;
#pragma unroll
            for (int d = 1; d < 64; d <<= 1) {
                int v = __shfl_up(incl, d, 64);
                if (lane >= d) incl += v;
            }
            int off = incl - cnt;
            unsigned int tmp = zb;
            while (tmp) {
                const int k = __ffs(tmp) - 1;
                tmp &= tmp - 1;
                s_idx[cur ^ 1][off++] = (unsigned short)(h0 + k);
            }
            n = __shfl(incl, 63, 64);
        }
#pragma unroll
        for (int k = 0; k < 16; ++k) xc[k] = xn[k];
        __syncthreads();   // single-wave: cheap; orders list writes vs reads
        cur ^= 1;
    }

    // write back state
#pragma unroll
    for (int k = 0; k < 16; ++k) {
        zS[(size_t)b * HID + h0 + k] = (zb >> k) & 1 ? 1.f : 0.f;
        uS[(size_t)b * HID + h0 + k] = u[k];
        aS[(size_t)b * HID + h0 + k] = a[k];
    }
#pragma unroll
    for (int d = 32; d > 0; d >>= 1) wspk += __shfl_down(wspk, d, 64);
    if (lane == 0) atomicAdd(spkS, (float)wspk);
}

// ---------------------------------------------------------------------------
// y[t*B+b][o] = sum over spiking j of WoT[j][o]  (one wave per (t,b) pair)
// ---------------------------------------------------------------------------
__global__ __launch_bounds__(256)
void readout_y(const u64* __restrict__ masks, const float* __restrict__ WoT,
               float* __restrict__ y, int npairs) {
    const int pr   = blockIdx.x * 4 + (threadIdx.x >> 6);
    const int lane = threadIdx.x & 63;
    if (pr >= npairs) return;
    const u64* mp = masks + (size_t)pr * 16;
    float acc = 0.f;
#pragma unroll 4
    for (int w = 0; w < 16; ++w) {
        u64 m = mp[w];
        while (m) {
            const int j = __ffsll((unsigned long long)m) - 1;
            m &= m - 1;
            if (lane < OUT_DIM) acc += WoT[(size_t)(w * 64 + j) * OUT_DIM + lane];
        }
    }
    if (lane < OUT_DIM) y[(size_t)pr * OUT_DIM + lane] = acc;
}

// ---------------------------------------------------------------------------
// outputs[t][b][o] = EWA over t of y; writes final ouT.
// ---------------------------------------------------------------------------
__global__ __launch_bounds__(256)
void ewa_out(const float* __restrict__ y, const float* __restrict__ tau_out,
             float* __restrict__ outputs, float* __restrict__ ouS) {
    const int idx = blockIdx.x * 256 + threadIdx.x;
    if (idx >= BATCH * OUT_DIM) return;
    const int o = idx % OUT_DIM;
    const float ao = expf(-1.f / tau_out[o]);
    float ou = ouS[idx];
    for (int t = 0; t < T_STEPS; ++t) {
        const float v = y[(size_t)t * BATCH * OUT_DIM + idx];
        ou = ao * ou + (1.f - ao) * v;
        outputs[(size_t)t * BATCH * OUT_DIM + idx] = ou;
    }
    ouS[idx] = ou;
}

// ---------------------------------------------------------------------------
extern "C" void kernel_launch(void* const* d_in, const int* in_sizes, int n_in,
                              void* d_out, int out_size, void* d_ws, size_t ws_size,
                              hipStream_t stream) {
    (void)in_sizes; (void)n_in; (void)out_size;
    const float* x       = (const float*)d_in[0];
    const float* W_h     = (const float*)d_in[1];
    const float* tau_mem = (const float*)d_in[2];
    const float* tau_adp = (const float*)d_in[3];
    const float* W_o     = (const float*)d_in[4];
    const float* tau_out = (const float*)d_in[5];

    float* out     = (float*)d_out;
    float* outputs = out;                                      // [250][256][20]
    float* zS  = out + (size_t)T_STEPS * BATCH * OUT_DIM;      // [256][1024]
    float* uS  = zS + (size_t)BATCH * HID;
    float* aS  = uS + (size_t)BATCH * HID;
    float* ouS = aS + (size_t)BATCH * HID;                     // [256][20]
    float* spk = ouS + (size_t)BATCH * OUT_DIM;                // scalar

    // ws layout (bytes)
    char* w = (char*)d_ws;
    unsigned short* WhhT = (unsigned short*)w; w += (size_t)(HID + 1) * HID * 2;  // 2 MB + zero row
    unsigned short* Wp   = (unsigned short*)w; w += (size_t)HID * KP * 2;         // 1.4 MB
    float*          WoT  = (float*)w;          w += (size_t)HID * OUT_DIM * 4;    // 80 KB
    unsigned short* masks16 = (unsigned short*)w; w += (size_t)T_STEPS * BATCH * 128; // 8 MB
    float*          yBuf = (float*)w;          w += (size_t)T_STEPS * BATCH * OUT_DIM * 4; // 5 MB
    char*           dynb = w;

    const size_t fixed = (size_t)(dynb - (char*)d_ws);
    const size_t per_step = (size_t)BATCH * KP * 2 + (size_t)BATCH * HID * 4;
    const size_t avail = ws_size > fixed ? ws_size - fixed : 0;
    int CT = (int)(avail / per_step);
    if (CT > T_STEPS) CT = T_STEPS;
    if (CT < 1) CT = 1;

    hipMemsetAsync(zS, 0,
                   ((size_t)3 * BATCH * HID + BATCH * OUT_DIM + 1) * sizeof(float),
                   stream);
    hipMemsetAsync(WhhT + (size_t)HID * HID, 0, HID * sizeof(unsigned short), stream);
    trans_whh_bf16<<<dim3(32, 32), dim3(32, 8), 0, stream>>>(W_h, WhhT);
    pack_w_bf16<<<512, 256, 0, stream>>>(W_h, Wp);
    trans_wo<<<4, 256, 0, stream>>>(W_o, WoT);

    for (int t0 = 0; t0 < T_STEPS; t0 += CT) {
        const int tc = (T_STEPS - t0 < CT) ? (T_STEPS - t0) : CT;
        const int rows = tc * BATCH;
        unsigned short* Xp = (unsigned short*)dynb;
        float* CUR = (float*)(dynb + (size_t)rows * KP * 2);
        int pblocks = (rows * KP4 + 255) / 256;
        if (pblocks > 2048) pblocks = 2048;
        pack_x_bf16<<<pblocks, 256, 0, stream>>>(x + (size_t)t0 * BATCH * IN_DIM, Xp, rows);
        mfma_gemm<<<dim3(rows / 128, HID / 128), 256, 0, stream>>>(Xp, Wp, CUR);
        alif_scan<<<BATCH, 64, 0, stream>>>(CUR, WhhT, tau_mem, tau_adp,
                                            zS, uS, aS, spk, masks16, t0, tc);
    }

    const int npairs = T_STEPS * BATCH;
    readout_y<<<(npairs + 3) / 4, 256, 0, stream>>>((const u64*)masks16, WoT, yBuf, npairs);
    ewa_out<<<(BATCH * OUT_DIM + 255) / 256, 256, 0, stream>>>(yBuf, tau_out, outputs, ouS);
}